// Round 6
// baseline (315.064 us; speedup 1.0000x reference)
//
#include <hip/hip_runtime.h>

// B=8, C=d=128, H=W=64, N=H*W=4096
#define NB 8
#define CD 128
#define NN 4096
#define KV 32                  // kv keys per tile (double-buffered)
#define SCALE 0.08838834764831845f
#define L2E 1.44269504088896f
#define QSCALE (SCALE * L2E)   // fold softmax scale AND log2(e) into Q

typedef __bf16 bf16x8 __attribute__((ext_vector_type(8)));
typedef float f32x4 __attribute__((ext_vector_type(4)));

// XOR swizzles on 16B blocks within a row; involution -> same fn write & read.
__device__ __forceinline__ unsigned swz256(unsigned row, unsigned b) {
  unsigned s = b >> 4, o = b & 15u;
  unsigned sw = (s & 8u) | ((s & 7u) ^ (row & 7u));
  return row * 256u + sw * 16u + o;
}
// 64B-row swizzle (4 slots of 16B): sw = (s ^ (row>>1)) & 3.
// Row stride 64B = 16 banks, so (row&1) splits halves; row>>1 spreads slots.
__device__ __forceinline__ unsigned swz64(unsigned row, unsigned b) {
  unsigned s = b >> 4, o = b & 15u;
  unsigned sw = (s ^ (row >> 1)) & 3u;
  return row * 64u + sw * 16u + o;
}

// DPP rotate-within-16 (VALU pipe, no LDS) for the row-max butterfly.
#define DPP_ROR_F(x, N)                                                       \
  __builtin_bit_cast(float, __builtin_amdgcn_update_dpp(                      \
      __builtin_bit_cast(int, (x)), __builtin_bit_cast(int, (x)),             \
      0x120 + (N), 0xF, 0xF, false))

// async global->LDS, 16B per lane; LDS dest = wave-uniform base + lane*16
__device__ __forceinline__ void gload16(const __bf16* g, unsigned char* l) {
  __builtin_amdgcn_global_load_lds(
      (const __attribute__((address_space(1))) void*)g,
      (__attribute__((address_space(3))) void*)l, 16, 0, 0);
}

// ---------------------------------------------------------------------------
// Kernel 1: fused transpose + QKV projection (unchanged from v3).
//  Q,K computed in split bf16 (3 MFMAs: hh+hl+lh) for ~fp32 logit accuracy.
//  Q carries SCALE*log2(e).  Grid is 1-D; batch = bid&7 -> XCD affinity.
// ---------------------------------------------------------------------------
__global__ __launch_bounds__(256, 2) void qkv_kernel(
    const float* __restrict__ x,
    const float* __restrict__ qw, const float* __restrict__ qb,
    const float* __restrict__ kw, const float* __restrict__ kb,
    const float* __restrict__ vw, const float* __restrict__ vb,
    __bf16* __restrict__ Qh, __bf16* __restrict__ Ql,
    __bf16* __restrict__ Kh, __bf16* __restrict__ Kl,
    __bf16* __restrict__ Vt)
{
  __shared__ __align__(16) unsigned char sm[49664];
  const int tid = threadIdx.x;
  const int lane = tid & 63, wv = tid >> 6;
  const int l15 = lane & 15, g = lane >> 4;
  const int b = blockIdx.x & 7;
  const int n0 = (blockIdx.x >> 3) * 64;
  const f32x4 Z4 = {0.f, 0.f, 0.f, 0.f};

  #pragma unroll 4
  for (int i = 0; i < 32; ++i) {
    int e = i * 256 + tid;
    int nl = e & 63, c = e >> 6;
    float f = x[((size_t)(b * CD + c)) * NN + n0 + nl];
    __bf16 h = (__bf16)f;
    __bf16 lo = (__bf16)(f - (float)h);
    unsigned off = swz256((unsigned)nl, (unsigned)(c * 2));
    *(__bf16*)(sm + off) = h;
    *(__bf16*)(sm + 16384 + off) = lo;
  }
  __syncthreads();

  bf16x8 ah[4], al[4];
  #pragma unroll
  for (int kk = 0; kk < 4; ++kk) {
    unsigned off = swz256((unsigned)(wv * 16 + l15), (unsigned)(kk * 64 + g * 16));
    ah[kk] = *(const bf16x8*)(sm + off);
    al[kk] = *(const bf16x8*)(sm + 16384 + off);
  }

  for (int mat = 0; mat < 2; ++mat) {
    const float* gw = mat ? kw : qw;
    const float* gb = mat ? kb : qb;
    __bf16* Oh = mat ? Kh : Qh;
    __bf16* Ol = mat ? Kl : Ql;
    const float sc = mat ? 1.0f : QSCALE;
    for (int qd = 0; qd < 4; ++qd) {
      #pragma unroll 4
      for (int i = 0; i < 16; ++i) {
        int e = i * 256 + tid;
        int dl = e & 31, c = e >> 5;
        float f = gw[c * CD + qd * 32 + dl];
        __bf16 h = (__bf16)f;
        __bf16 lo = (__bf16)(f - (float)h);
        unsigned off = swz256((unsigned)dl, (unsigned)(c * 2));
        *(__bf16*)(sm + 32768 + off) = h;
        *(__bf16*)(sm + 40960 + off) = lo;
      }
      __syncthreads();
      #pragma unroll
      for (int fr = 0; fr < 2; ++fr) {
        f32x4 acc = Z4;
        #pragma unroll
        for (int kk = 0; kk < 4; ++kk) {
          unsigned off = swz256((unsigned)(fr * 16 + l15), (unsigned)(kk * 64 + g * 16));
          bf16x8 bh = *(const bf16x8*)(sm + 32768 + off);
          bf16x8 bl = *(const bf16x8*)(sm + 40960 + off);
          acc = __builtin_amdgcn_mfma_f32_16x16x32_bf16(ah[kk], bh, acc, 0, 0, 0);
          acc = __builtin_amdgcn_mfma_f32_16x16x32_bf16(ah[kk], bl, acc, 0, 0, 0);
          acc = __builtin_amdgcn_mfma_f32_16x16x32_bf16(al[kk], bh, acc, 0, 0, 0);
        }
        const int dout = qd * 32 + fr * 16 + l15;
        const float bias = gb[dout];
        #pragma unroll
        for (int r = 0; r < 4; ++r) {
          int row = n0 + wv * 16 + g * 4 + r;
          float v = (acc[r] + bias) * sc;
          __bf16 h = (__bf16)v;
          __bf16 lo = (__bf16)(v - (float)h);
          size_t go = ((size_t)(b * NN + row)) * CD + dout;
          Oh[go] = h;
          Ol[go] = lo;
        }
      }
      __syncthreads();
    }
  }

  f32x4 accV[8];
  #pragma unroll
  for (int i = 0; i < 8; ++i) accV[i] = Z4;
  for (int qd = 0; qd < 4; ++qd) {
    #pragma unroll 4
    for (int i = 0; i < 16; ++i) {
      int e = i * 256 + tid;
      int dl = e & 31, c = e >> 5;
      float f = vw[c * CD + qd * 32 + dl];
      *(__bf16*)(sm + 32768 + swz256((unsigned)dl, (unsigned)(c * 2))) = (__bf16)f;
    }
    __syncthreads();
    #pragma unroll
    for (int fr = 0; fr < 2; ++fr) {
      f32x4 acc = accV[qd * 2 + fr];
      #pragma unroll
      for (int kk = 0; kk < 4; ++kk) {
        unsigned off = swz256((unsigned)(fr * 16 + l15), (unsigned)(kk * 64 + g * 16));
        bf16x8 bh = *(const bf16x8*)(sm + 32768 + off);
        acc = __builtin_amdgcn_mfma_f32_16x16x32_bf16(ah[kk], bh, acc, 0, 0, 0);
      }
      accV[qd * 2 + fr] = acc;
    }
    __syncthreads();
  }
  #pragma unroll
  for (int df = 0; df < 8; ++df) {
    int dout = df * 16 + l15;
    float bias = vb[dout];
    #pragma unroll
    for (int r = 0; r < 4; ++r) {
      int row = wv * 16 + g * 4 + r;
      *(__bf16*)(sm + 32768 + (row * 132 + dout) * 2) = (__bf16)(accV[df][r] + bias);
    }
  }
  __syncthreads();
  #pragma unroll 4
  for (int i = 0; i < 32; ++i) {
    int e = i * 256 + tid;
    int nl = e & 63, dout = e >> 6;
    __bf16 v = *(const __bf16*)(sm + 32768 + (nl * 132 + dout) * 2);
    Vt[((size_t)(b * CD + dout)) * NN + n0 + nl] = v;
  }
}

// ---------------------------------------------------------------------------
// Kernel 2: flash attention v4.
//  KVBLK=32, K/V double-buffered, staged via global_load_lds (16B) with
//  pre-swizzled GLOBAL source + linear LDS dest (G21 both-sides rule).
//  One barrier per tile; loads for t+1 fly under tile t's compute.
//  52KB LDS -> 3 blocks/CU (12 waves). Split-bf16 QK^T unchanged.
// ---------------------------------------------------------------------------
__global__ __launch_bounds__(256, 3) void attn_kernel(
    const __bf16* __restrict__ Qh, const __bf16* __restrict__ Ql,
    const __bf16* __restrict__ Kh, const __bf16* __restrict__ Kl,
    const __bf16* __restrict__ Vt, const float* __restrict__ x,
    const float* __restrict__ pw, const float* __restrict__ pb,
    float* __restrict__ out)
{
  // loop: KH c=0/1:[0,16384) KL:[16384,32768) VT:[32768,49152) P:[49152,53248)
  // epilogue: O:[0,16384) PWT:[16384,49152)
  __shared__ __align__(16) unsigned char sm[53248];
  const int tid = threadIdx.x;
  const int lane = tid & 63, wv = tid >> 6;
  const int l15 = lane & 15, g = lane >> 4;
  const int b = blockIdx.x & 7;           // batch -> XCD (round-robin dispatch)
  const int q0 = (blockIdx.x >> 3) * 64;
  const f32x4 Z4 = {0.f, 0.f, 0.f, 0.f};

  // Q fragments (hi/lo) straight from global into registers
  bf16x8 qh[4], ql[4];
  #pragma unroll
  for (int kk = 0; kk < 4; ++kk) {
    size_t off = ((size_t)(b * NN + q0 + wv * 16 + l15)) * CD + kk * 32 + g * 8;
    qh[kk] = *(const bf16x8*)(Qh + off);
    ql[kk] = *(const bf16x8*)(Ql + off);
  }

  // constant ones-column B fragment: col 0 of B = 1.0 along all k
  bf16x8 bones;
  {
    __bf16 v = (l15 == 0) ? (__bf16)1.0f : (__bf16)0.0f;
    #pragma unroll
    for (int j = 0; j < 8; ++j) bones[j] = v;
  }

  f32x4 accO[8];
  #pragma unroll
  for (int i = 0; i < 8; ++i) accO[i] = Z4;
  f32x4 accL = Z4;                 // row-sum accumulator (valid in l15==0 lanes)
  float mrow[4];
  #pragma unroll
  for (int r = 0; r < 4; ++r) mrow[r] = -__builtin_inff();

  // async staging: pre-swizzled global source, linear LDS dest (lane*16).
  // K tile [32 rows][256B]: wave wv stages rows wv*8..+7 (2 insts x 4 rows).
  // V tile [128 rows][64B]: wave wv stages rows (wv*2+i)*16..+15 (2 insts).
  #define ISSUE(KT, BUF)                                                       \
    {                                                                          \
      const int kb_ = b * NN + (KT) * KV;                                      \
      _Pragma("unroll")                                                        \
      for (int i = 0; i < 2; ++i) {                                            \
        int rowK = wv * 8 + i * 4 + (lane >> 4);                               \
        int sw16 = lane & 15;                                                  \
        int sK_ = (sw16 & 8) | ((sw16 & 7) ^ (rowK & 7));                      \
        gload16(Kh + (size_t)(kb_ + rowK) * CD + sK_ * 8,                      \
                sm + (BUF) * 8192 + (wv * 8 + i * 4) * 256);                   \
        gload16(Kl + (size_t)(kb_ + rowK) * CD + sK_ * 8,                      \
                sm + 16384 + (BUF) * 8192 + (wv * 8 + i * 4) * 256);           \
        int rowV = (wv * 2 + i) * 16 + (lane >> 2);                            \
        int sV_ = ((lane & 3) ^ (rowV >> 1)) & 3;                              \
        gload16(Vt + ((size_t)(b * CD) + rowV) * NN + (KT) * KV + sV_ * 8,     \
                sm + 32768 + (BUF) * 8192 + ((wv * 2 + i) * 16) * 64);         \
      }                                                                        \
    }

  ISSUE(0, 0);
  __syncthreads();              // vmcnt(0) drain: tile 0 landed

  for (int kt = 0; kt < 128; ++kt) {
    const int cur = kt & 1;
    if (kt < 127) ISSUE(kt + 1, cur ^ 1);   // fly under this tile's compute
    __builtin_amdgcn_sched_barrier(0);      // pin load issue before MFMAs

    // S = Qs * K^T  (split: hh + hl + lh), logits already in log2 domain
    f32x4 s4[2];
    #pragma unroll
    for (int kf = 0; kf < 2; ++kf) s4[kf] = Z4;
    __builtin_amdgcn_s_setprio(1);
    #pragma unroll
    for (int kf = 0; kf < 2; ++kf) {
      #pragma unroll
      for (int kk = 0; kk < 4; ++kk) {
        unsigned off = (unsigned)(cur * 8192) +
                       swz256((unsigned)(kf * 16 + l15), (unsigned)(kk * 64 + g * 16));
        bf16x8 bh = *(const bf16x8*)(sm + off);
        bf16x8 bl = *(const bf16x8*)(sm + 16384 + off);
        s4[kf] = __builtin_amdgcn_mfma_f32_16x16x32_bf16(qh[kk], bh, s4[kf], 0, 0, 0);
        s4[kf] = __builtin_amdgcn_mfma_f32_16x16x32_bf16(qh[kk], bl, s4[kf], 0, 0, 0);
        s4[kf] = __builtin_amdgcn_mfma_f32_16x16x32_bf16(ql[kk], bh, s4[kf], 0, 0, 0);
      }
    }
    __builtin_amdgcn_s_setprio(0);

    // online softmax: row-max via DPP rotations (VALU pipe, no LDS)
    float mnew[4];
    bool grow = false;
    #pragma unroll
    for (int r = 0; r < 4; ++r) {
      float mx = fmaxf(s4[0][r], s4[1][r]);
      mx = fmaxf(mx, DPP_ROR_F(mx, 8));
      mx = fmaxf(mx, DPP_ROR_F(mx, 4));
      mx = fmaxf(mx, DPP_ROR_F(mx, 2));
      mx = fmaxf(mx, DPP_ROR_F(mx, 1));
      float mn = fmaxf(mrow[r], mx);
      mnew[r] = mn;
      grow = grow || (mn > mrow[r]);
      #pragma unroll
      for (int kf = 0; kf < 2; ++kf)
        s4[kf][r] = exp2f(s4[kf][r] - mn);
    }
    if (__any((int)grow)) {          // defer-rescale: usually skipped
      #pragma unroll
      for (int r = 0; r < 4; ++r) {
        float alpha = exp2f(mrow[r] - mnew[r]);
        accL[r] *= alpha;
        #pragma unroll
        for (int df = 0; df < 8; ++df) accO[df][r] *= alpha;
      }
    }
    #pragma unroll
    for (int r = 0; r < 4; ++r) mrow[r] = mnew[r];

    // write P (bf16) to this wave's private LDS rows (wave-local, no barrier)
    #pragma unroll
    for (int kf = 0; kf < 2; ++kf) {
      #pragma unroll
      for (int r = 0; r < 4; ++r) {
        unsigned row = (unsigned)(wv * 16 + g * 4 + r);
        *(__bf16*)(sm + 49152 + swz64(row, (unsigned)((kf * 16 + l15) * 2))) =
            (__bf16)s4[kf][r];
      }
    }

    // O += P * V ; row-sum l += P * ones
    bf16x8 pa = *(const bf16x8*)(sm + 49152 +
                  swz64((unsigned)(wv * 16 + l15), (unsigned)(g * 16)));
    __builtin_amdgcn_s_setprio(1);
    accL = __builtin_amdgcn_mfma_f32_16x16x32_bf16(pa, bones, accL, 0, 0, 0);
    #pragma unroll
    for (int df = 0; df < 8; ++df) {
      bf16x8 bv = *(const bf16x8*)(sm + 32768 + cur * 8192 +
                    swz64((unsigned)(df * 16 + l15), (unsigned)(g * 16)));
      accO[df] = __builtin_amdgcn_mfma_f32_16x16x32_bf16(pa, bv, accO[df], 0, 0, 0);
    }
    __builtin_amdgcn_s_setprio(0);

    __syncthreads();   // reads of tile kt done; t+1 loads drained (vmcnt(0))
  }
  #undef ISSUE

  // epilogue: broadcast row-sums from l15==0 lanes, O/l -> bf16 LDS,
  // stage proj_w^T, hout = O @ pw + pb + residual
  float rl[4];
  #pragma unroll
  for (int r = 0; r < 4; ++r) {
    float lv = __shfl(accL[r], lane & 48);   // this group's l15==0 lane
    rl[r] = 1.0f / lv;
  }
  #pragma unroll
  for (int df = 0; df < 8; ++df) {
    #pragma unroll
    for (int r = 0; r < 4; ++r) {
      unsigned row = (unsigned)(wv * 16 + g * 4 + r);
      *(__bf16*)(sm + swz256(row, (unsigned)((df * 16 + l15) * 2))) =
          (__bf16)(accO[df][r] * rl[r]);
    }
  }
  #pragma unroll 4
  for (int i = 0; i < 16; ++i) {  // pwT[dout][c] bf16 at 16384
    int e = i * 256 + tid;
    int c = e >> 5, d4 = e & 31;
    const float4 w4 = *(const float4*)(pw + c * CD + d4 * 4);
    *(__bf16*)(sm + 16384 + swz256((unsigned)(d4 * 4 + 0), (unsigned)(c * 2))) = (__bf16)w4.x;
    *(__bf16*)(sm + 16384 + swz256((unsigned)(d4 * 4 + 1), (unsigned)(c * 2))) = (__bf16)w4.y;
    *(__bf16*)(sm + 16384 + swz256((unsigned)(d4 * 4 + 2), (unsigned)(c * 2))) = (__bf16)w4.z;
    *(__bf16*)(sm + 16384 + swz256((unsigned)(d4 * 4 + 3), (unsigned)(c * 2))) = (__bf16)w4.w;
  }
  __syncthreads();

  bf16x8 oa[4];
  #pragma unroll
  for (int kk = 0; kk < 4; ++kk)
    oa[kk] = *(const bf16x8*)(sm + swz256((unsigned)(wv * 16 + l15),
                                          (unsigned)(kk * 64 + g * 16)));
  #pragma unroll
  for (int df = 0; df < 8; ++df) {
    f32x4 acc = Z4;
    #pragma unroll
    for (int kk = 0; kk < 4; ++kk) {
      bf16x8 bw = *(const bf16x8*)(sm + 16384 +
                    swz256((unsigned)(df * 16 + l15), (unsigned)(kk * 64 + g * 16)));
      acc = __builtin_amdgcn_mfma_f32_16x16x32_bf16(oa[kk], bw, acc, 0, 0, 0);
    }
    const int cc = df * 16 + l15;
    const float bias = pb[cc];
    #pragma unroll
    for (int r = 0; r < 4; ++r) {
      int row = q0 + wv * 16 + g * 4 + r;
      float val = acc[r] + bias + x[((size_t)(b * CD + cc)) * NN + row];
      out[((size_t)(b * NN + row)) * CD + cc] = val;
    }
  }
}

// ---------------------------------------------------------------------------
extern "C" void kernel_launch(void* const* d_in, const int* in_sizes, int n_in,
                              void* d_out, int out_size, void* d_ws, size_t ws_size,
                              hipStream_t stream) {
  (void)in_sizes; (void)n_in; (void)out_size; (void)ws_size;
  const float* x  = (const float*)d_in[0];
  const float* qw = (const float*)d_in[1];
  const float* qb = (const float*)d_in[2];
  const float* kw = (const float*)d_in[3];
  const float* kb = (const float*)d_in[4];
  const float* vw = (const float*)d_in[5];
  const float* vb = (const float*)d_in[6];
  const float* pw = (const float*)d_in[7];
  const float* pb = (const float*)d_in[8];
  float* out = (float*)d_out;

  const size_t SZ = (size_t)NB * NN * CD;  // 4.19M elems per buffer
  __bf16* Qh = (__bf16*)d_ws;              // ws usage: 5 * 8.39 MB = 41.9 MB
  __bf16* Ql = Qh + SZ;
  __bf16* Kh = Ql + SZ;
  __bf16* Kl = Kh + SZ;
  __bf16* Vt = Kl + SZ;

  dim3 grid(512), blk(256);                // 1-D: bid&7 = batch = XCD
  qkv_kernel<<<grid, blk, 0, stream>>>(x, qw, qb, kw, kb, vw, vb,
                                       Qh, Ql, Kh, Kl, Vt);
  attn_kernel<<<grid, blk, 0, stream>>>(Qh, Ql, Kh, Kl, Vt, x, pw, pb, out);
}

// Round 7
// 297.485 us; speedup vs baseline: 1.0591x; 1.0591x over previous
//
#include <hip/hip_runtime.h>

// B=8, C=d=128, H=W=64, N=H*W=4096
#define NB 8
#define CD 128
#define NN 4096
#define KV 64                  // kv keys per tile
#define SCALE 0.08838834764831845f
#define L2E 1.44269504088896f
#define QSCALE (SCALE * L2E)   // fold softmax scale AND log2(e) into Q

typedef __bf16 bf16x8 __attribute__((ext_vector_type(8)));
typedef float f32x4 __attribute__((ext_vector_type(4)));

// XOR swizzles on 16B blocks within a row; involution -> same fn write & read.
__device__ __forceinline__ unsigned swz256(unsigned row, unsigned b) {
  unsigned s = b >> 4, o = b & 15u;
  unsigned sw = (s & 8u) | ((s & 7u) ^ (row & 7u));
  return row * 256u + sw * 16u + o;
}
__device__ __forceinline__ unsigned swz128(unsigned row, unsigned b) {
  unsigned s = b >> 4, o = b & 15u;
  unsigned sw = (s ^ row) & 7u;
  return row * 128u + sw * 16u + o;
}

// v_cvt_pk_bf16_f32: dst = {bf16(lo) in [15:0], bf16(hi) in [31:16]}
__device__ __forceinline__ int cvt_pk_bf16(float lo, float hi) {
  int w;
  asm("v_cvt_pk_bf16_f32 %0, %1, %2" : "=v"(w) : "v"(lo), "v"(hi));
  return w;
}

// ---------------------------------------------------------------------------
// Kernel 1: fused transpose + QKV projection (unchanged from v3).
// ---------------------------------------------------------------------------
__global__ __launch_bounds__(256, 2) void qkv_kernel(
    const float* __restrict__ x,
    const float* __restrict__ qw, const float* __restrict__ qb,
    const float* __restrict__ kw, const float* __restrict__ kb,
    const float* __restrict__ vw, const float* __restrict__ vb,
    __bf16* __restrict__ Qh, __bf16* __restrict__ Ql,
    __bf16* __restrict__ Kh, __bf16* __restrict__ Kl,
    __bf16* __restrict__ Vt)
{
  __shared__ __align__(16) unsigned char sm[49664];
  const int tid = threadIdx.x;
  const int lane = tid & 63, wv = tid >> 6;
  const int l15 = lane & 15, g = lane >> 4;
  const int b = blockIdx.x & 7;
  const int n0 = (blockIdx.x >> 3) * 64;
  const f32x4 Z4 = {0.f, 0.f, 0.f, 0.f};

  #pragma unroll 4
  for (int i = 0; i < 32; ++i) {
    int e = i * 256 + tid;
    int nl = e & 63, c = e >> 6;
    float f = x[((size_t)(b * CD + c)) * NN + n0 + nl];
    __bf16 h = (__bf16)f;
    __bf16 lo = (__bf16)(f - (float)h);
    unsigned off = swz256((unsigned)nl, (unsigned)(c * 2));
    *(__bf16*)(sm + off) = h;
    *(__bf16*)(sm + 16384 + off) = lo;
  }
  __syncthreads();

  bf16x8 ah[4], al[4];
  #pragma unroll
  for (int kk = 0; kk < 4; ++kk) {
    unsigned off = swz256((unsigned)(wv * 16 + l15), (unsigned)(kk * 64 + g * 16));
    ah[kk] = *(const bf16x8*)(sm + off);
    al[kk] = *(const bf16x8*)(sm + 16384 + off);
  }

  for (int mat = 0; mat < 2; ++mat) {
    const float* gw = mat ? kw : qw;
    const float* gb = mat ? kb : qb;
    __bf16* Oh = mat ? Kh : Qh;
    __bf16* Ol = mat ? Kl : Ql;
    const float sc = mat ? 1.0f : QSCALE;
    for (int qd = 0; qd < 4; ++qd) {
      #pragma unroll 4
      for (int i = 0; i < 16; ++i) {
        int e = i * 256 + tid;
        int dl = e & 31, c = e >> 5;
        float f = gw[c * CD + qd * 32 + dl];
        __bf16 h = (__bf16)f;
        __bf16 lo = (__bf16)(f - (float)h);
        unsigned off = swz256((unsigned)dl, (unsigned)(c * 2));
        *(__bf16*)(sm + 32768 + off) = h;
        *(__bf16*)(sm + 40960 + off) = lo;
      }
      __syncthreads();
      #pragma unroll
      for (int fr = 0; fr < 2; ++fr) {
        f32x4 acc = Z4;
        #pragma unroll
        for (int kk = 0; kk < 4; ++kk) {
          unsigned off = swz256((unsigned)(fr * 16 + l15), (unsigned)(kk * 64 + g * 16));
          bf16x8 bh = *(const bf16x8*)(sm + 32768 + off);
          bf16x8 bl = *(const bf16x8*)(sm + 40960 + off);
          acc = __builtin_amdgcn_mfma_f32_16x16x32_bf16(ah[kk], bh, acc, 0, 0, 0);
          acc = __builtin_amdgcn_mfma_f32_16x16x32_bf16(ah[kk], bl, acc, 0, 0, 0);
          acc = __builtin_amdgcn_mfma_f32_16x16x32_bf16(al[kk], bh, acc, 0, 0, 0);
        }
        const int dout = qd * 32 + fr * 16 + l15;
        const float bias = gb[dout];
        #pragma unroll
        for (int r = 0; r < 4; ++r) {
          int row = n0 + wv * 16 + g * 4 + r;
          float v = (acc[r] + bias) * sc;
          __bf16 h = (__bf16)v;
          __bf16 lo = (__bf16)(v - (float)h);
          size_t go = ((size_t)(b * NN + row)) * CD + dout;
          Oh[go] = h;
          Ol[go] = lo;
        }
      }
      __syncthreads();
    }
  }

  f32x4 accV[8];
  #pragma unroll
  for (int i = 0; i < 8; ++i) accV[i] = Z4;
  for (int qd = 0; qd < 4; ++qd) {
    #pragma unroll 4
    for (int i = 0; i < 16; ++i) {
      int e = i * 256 + tid;
      int dl = e & 31, c = e >> 5;
      float f = vw[c * CD + qd * 32 + dl];
      *(__bf16*)(sm + 32768 + swz256((unsigned)dl, (unsigned)(c * 2))) = (__bf16)f;
    }
    __syncthreads();
    #pragma unroll
    for (int fr = 0; fr < 2; ++fr) {
      f32x4 acc = accV[qd * 2 + fr];
      #pragma unroll
      for (int kk = 0; kk < 4; ++kk) {
        unsigned off = swz256((unsigned)(fr * 16 + l15), (unsigned)(kk * 64 + g * 16));
        bf16x8 bh = *(const bf16x8*)(sm + 32768 + off);
        acc = __builtin_amdgcn_mfma_f32_16x16x32_bf16(ah[kk], bh, acc, 0, 0, 0);
      }
      accV[qd * 2 + fr] = acc;
    }
    __syncthreads();
  }
  #pragma unroll
  for (int df = 0; df < 8; ++df) {
    int dout = df * 16 + l15;
    float bias = vb[dout];
    #pragma unroll
    for (int r = 0; r < 4; ++r) {
      int row = wv * 16 + g * 4 + r;
      *(__bf16*)(sm + 32768 + (row * 132 + dout) * 2) = (__bf16)(accV[df][r] + bias);
    }
  }
  __syncthreads();
  #pragma unroll 4
  for (int i = 0; i < 32; ++i) {
    int e = i * 256 + tid;
    int nl = e & 63, dout = e >> 6;
    __bf16 v = *(const __bf16*)(sm + 32768 + (nl * 132 + dout) * 2);
    Vt[((size_t)(b * CD + dout)) * NN + n0 + nl] = v;
  }
}

// ---------------------------------------------------------------------------
// Kernel 2: flash attention v5.
//  Swapped-operand QK^T: mfma(K, Q) -> lane holds P[16 keys][q=l15].
//  Softmax: lane-local max tree + 2 shfl_xor; P never touches LDS --
//  cvt_pk + ds_bpermute transpose builds PV A-fragments in registers.
//  K/V staging, V reads, accO/accL, epilogue identical to v3 (217us base).
// ---------------------------------------------------------------------------
__global__ __launch_bounds__(256, 2) void attn_kernel(
    const __bf16* __restrict__ Qh, const __bf16* __restrict__ Ql,
    const __bf16* __restrict__ Kh, const __bf16* __restrict__ Kl,
    const __bf16* __restrict__ Vt, const float* __restrict__ x,
    const float* __restrict__ pw, const float* __restrict__ pb,
    float* __restrict__ out)
{
  // loop:     KH:[0,16384) KL:[16384,32768) VT:[32768,49152)
  // epilogue: O:[0,16384)  PWT:[16384,49152)
  __shared__ __align__(16) unsigned char sm[49152];
  const int tid = threadIdx.x;
  const int lane = tid & 63, wv = tid >> 6;
  const int l15 = lane & 15, g = lane >> 4;
  const int b = blockIdx.x & 7;           // batch -> XCD (round-robin dispatch)
  const int q0 = (blockIdx.x >> 3) * 64;
  const f32x4 Z4 = {0.f, 0.f, 0.f, 0.f};

  // Q fragments (hi/lo): in swapped mode Q is the B operand; lane needs
  // Q[q=l15][c=g*8..+7 + kk*32] -- same addresses as v3.
  bf16x8 qh[4], ql[4];
  #pragma unroll
  for (int kk = 0; kk < 4; ++kk) {
    size_t off = ((size_t)(b * NN + q0 + wv * 16 + l15)) * CD + kk * 32 + g * 8;
    qh[kk] = *(const bf16x8*)(Qh + off);
    ql[kk] = *(const bf16x8*)(Ql + off);
  }

  // constant ones-column B fragment: col 0 of B = 1.0 along all k
  bf16x8 bones;
  {
    __bf16 v = (l15 == 0) ? (__bf16)1.0f : (__bf16)0.0f;
    #pragma unroll
    for (int j = 0; j < 8; ++j) bones[j] = v;
  }

  f32x4 accO[8];
  #pragma unroll
  for (int i = 0; i < 8; ++i) accO[i] = Z4;
  f32x4 accL = Z4;                 // row-sums land in l15==0 lanes (col 0)
  float mrow = -__builtin_inff();  // running max for q = l15 (one per lane)

  // staging (v3 reg-staged pattern) with hoisted per-lane offsets
  bf16x8 pkh[4], pkl[4], pvv[4];
  const int rK = tid >> 4, sK = tid & 15;
  const int rV = tid >> 3, sV = tid & 7;
  const __bf16* bKh = Kh + (size_t)(b * NN) * CD;
  const __bf16* bKl = Kl + (size_t)(b * NN) * CD;
  const __bf16* bVt = Vt + (size_t)(b * CD) * NN;
  int offK[4], offV[4];
  #pragma unroll
  for (int i = 0; i < 4; ++i) {
    offK[i] = (i * 16 + rK) * CD + sK * 8;
    offV[i] = (i * 32 + rV) * NN + sV * 8;
  }
  // bpermute lane addresses (bytes = lane*4), loop-invariant
  const int baseAddr = ((g & 1) * 32 + l15) * 4;   // g_s = (g&1)*2 (+1 for w>=2)
  const int addrA = (g * 4) * 4;                   // alpha sources: lanes q=g*4+r

  #define ISSUE(KTOFFK, KTOFFV)                                                \
    {                                                                          \
      _Pragma("unroll")                                                        \
      for (int i = 0; i < 4; ++i) {                                            \
        pkh[i] = *(const bf16x8*)(bKh + (KTOFFK) + offK[i]);                   \
        pkl[i] = *(const bf16x8*)(bKl + (KTOFFK) + offK[i]);                   \
        pvv[i] = *(const bf16x8*)(bVt + (KTOFFV) + offV[i]);                   \
      }                                                                        \
    }
  #define COMMIT()                                                             \
    {                                                                          \
      _Pragma("unroll")                                                        \
      for (int i = 0; i < 4; ++i) {                                            \
        unsigned o_ = swz256((unsigned)(i * 16 + rK), (unsigned)(sK * 16));    \
        *(bf16x8*)(sm + o_) = pkh[i];                                          \
        *(bf16x8*)(sm + 16384 + o_) = pkl[i];                                  \
        *(bf16x8*)(sm + 32768 +                                                \
                   swz128((unsigned)(i * 32 + rV), (unsigned)(sV * 16))) = pvv[i]; \
      }                                                                        \
    }

  ISSUE(0, 0);
  COMMIT();
  __syncthreads();

  int ktoffK = KV * CD, ktoffV = KV;     // uniform, bumped per tile
  for (int kt = 0; kt < 64; ++kt) {
    if (kt < 63) ISSUE(ktoffK, ktoffV);  // latency hides under this tile
    ktoffK += KV * CD;
    ktoffV += KV;
    __builtin_amdgcn_sched_barrier(0);   // pin load issue before MFMAs

    // S^T = K * Q^T (swapped): s4[kf][r] = P[key=kf*16+g*4+r][q=l15]
    f32x4 s4[4];
    #pragma unroll
    for (int kf = 0; kf < 4; ++kf) s4[kf] = Z4;
    __builtin_amdgcn_s_setprio(1);
    #pragma unroll
    for (int kf = 0; kf < 4; ++kf) {
      #pragma unroll
      for (int kk = 0; kk < 4; ++kk) {
        unsigned off = swz256((unsigned)(kf * 16 + l15), (unsigned)(kk * 64 + g * 16));
        bf16x8 bh = *(const bf16x8*)(sm + off);
        bf16x8 bl = *(const bf16x8*)(sm + 16384 + off);
        s4[kf] = __builtin_amdgcn_mfma_f32_16x16x32_bf16(bh, qh[kk], s4[kf], 0, 0, 0);
        s4[kf] = __builtin_amdgcn_mfma_f32_16x16x32_bf16(bl, qh[kk], s4[kf], 0, 0, 0);
        s4[kf] = __builtin_amdgcn_mfma_f32_16x16x32_bf16(bh, ql[kk], s4[kf], 0, 0, 0);
      }
    }
    __builtin_amdgcn_s_setprio(0);

    // online softmax for q=l15: local max over 16 keys + cross-g reduce
    float mx = fmaxf(fmaxf(s4[0][0], s4[0][1]), fmaxf(s4[0][2], s4[0][3]));
    #pragma unroll
    for (int kf = 1; kf < 4; ++kf) {
      mx = fmaxf(mx, fmaxf(fmaxf(s4[kf][0], s4[kf][1]),
                           fmaxf(s4[kf][2], s4[kf][3])));
    }
    mx = fmaxf(mx, __shfl_xor(mx, 16));
    mx = fmaxf(mx, __shfl_xor(mx, 32));
    const float mn = fmaxf(mrow, mx);
    const bool grow = mn > mrow;
    #pragma unroll
    for (int kf = 0; kf < 4; ++kf) {
      #pragma unroll
      for (int r = 0; r < 4; ++r) s4[kf][r] = exp2f(s4[kf][r] - mn);
    }
    if (__any((int)grow)) {            // defer-rescale: usually skipped
      float alpha = exp2f(mrow - mn);
      int aw = __builtin_bit_cast(int, alpha);
      #pragma unroll
      for (int r = 0; r < 4; ++r) {
        // alpha for accO/accL row q = g*4+r, fetched from lane (g*4+r)
        float ar = __builtin_bit_cast(float,
                     __builtin_amdgcn_ds_bpermute(addrA + r * 4, aw));
        accL[r] *= ar;
        #pragma unroll
        for (int df = 0; df < 8; ++df) accO[df][r] *= ar;
      }
    }
    mrow = mn;

    // P -> bf16 PV A-fragments, fully in registers:
    //  c01/c23 = packed key pairs; bpermute gathers across the 4 g-groups.
    int c01[4], c23[4];
    #pragma unroll
    for (int kf = 0; kf < 4; ++kf) {
      c01[kf] = cvt_pk_bf16(s4[kf][0], s4[kf][1]);
      c23[kf] = cvt_pk_bf16(s4[kf][2], s4[kf][3]);
    }
    bf16x8 pa[2];
    #pragma unroll
    for (int kk2 = 0; kk2 < 2; ++kk2) {
      int w[4];
      #pragma unroll
      for (int wi = 0; wi < 4; ++wi) {
        int se = (wi & 1) ? c23[kk2 * 2] : c01[kk2 * 2];        // kf even
        int so = (wi & 1) ? c23[kk2 * 2 + 1] : c01[kk2 * 2 + 1]; // kf odd
        int a = baseAddr + (wi >> 1) * 64;
        int ve = __builtin_amdgcn_ds_bpermute(a, se);
        int vo = __builtin_amdgcn_ds_bpermute(a, so);
        w[wi] = (g < 2) ? ve : vo;
      }
      int4 wv4 = {w[0], w[1], w[2], w[3]};
      pa[kk2] = __builtin_bit_cast(bf16x8, wv4);
    }

    // O += P * V ; row-sum l += P * ones (denominator matches bf16 P)
    __builtin_amdgcn_s_setprio(1);
    accL = __builtin_amdgcn_mfma_f32_16x16x32_bf16(pa[0], bones, accL, 0, 0, 0);
    accL = __builtin_amdgcn_mfma_f32_16x16x32_bf16(pa[1], bones, accL, 0, 0, 0);
    #pragma unroll
    for (int df = 0; df < 8; ++df) {
      #pragma unroll
      for (int kk2 = 0; kk2 < 2; ++kk2) {
        bf16x8 bv = *(const bf16x8*)(sm + 32768 +
                      swz128((unsigned)(df * 16 + l15), (unsigned)(kk2 * 64 + g * 16)));
        accO[df] = __builtin_amdgcn_mfma_f32_16x16x32_bf16(pa[kk2], bv, accO[df], 0, 0, 0);
      }
    }
    __builtin_amdgcn_s_setprio(0);

    __syncthreads();                  // all waves done reading K/V of tile kt
    if (kt < 63) COMMIT();
    __syncthreads();
  }
  #undef ISSUE
  #undef COMMIT

  // epilogue: broadcast row-sums from l15==0 lanes, O/l -> bf16 LDS,
  // stage proj_w^T, hout = O @ pw + pb + residual
  float rl[4];
  #pragma unroll
  for (int r = 0; r < 4; ++r) {
    float lv = __shfl(accL[r], lane & 48);   // this group's l15==0 lane
    rl[r] = 1.0f / lv;
  }
  #pragma unroll
  for (int df = 0; df < 8; ++df) {
    #pragma unroll
    for (int r = 0; r < 4; ++r) {
      unsigned row = (unsigned)(wv * 16 + g * 4 + r);
      *(__bf16*)(sm + swz256(row, (unsigned)((df * 16 + l15) * 2))) =
          (__bf16)(accO[df][r] * rl[r]);
    }
  }
  #pragma unroll 4
  for (int i = 0; i < 16; ++i) {  // pwT[dout][c] bf16 at 16384
    int e = i * 256 + tid;
    int c = e >> 5, d4 = e & 31;
    const float4 w4 = *(const float4*)(pw + c * CD + d4 * 4);
    *(__bf16*)(sm + 16384 + swz256((unsigned)(d4 * 4 + 0), (unsigned)(c * 2))) = (__bf16)w4.x;
    *(__bf16*)(sm + 16384 + swz256((unsigned)(d4 * 4 + 1), (unsigned)(c * 2))) = (__bf16)w4.y;
    *(__bf16*)(sm + 16384 + swz256((unsigned)(d4 * 4 + 2), (unsigned)(c * 2))) = (__bf16)w4.z;
    *(__bf16*)(sm + 16384 + swz256((unsigned)(d4 * 4 + 3), (unsigned)(c * 2))) = (__bf16)w4.w;
  }
  __syncthreads();

  bf16x8 oa[4];
  #pragma unroll
  for (int kk = 0; kk < 4; ++kk)
    oa[kk] = *(const bf16x8*)(sm + swz256((unsigned)(wv * 16 + l15),
                                          (unsigned)(kk * 64 + g * 16)));
  #pragma unroll
  for (int df = 0; df < 8; ++df) {
    f32x4 acc = Z4;
    #pragma unroll
    for (int kk = 0; kk < 4; ++kk) {
      bf16x8 bw = *(const bf16x8*)(sm + 16384 +
                    swz256((unsigned)(df * 16 + l15), (unsigned)(kk * 64 + g * 16)));
      acc = __builtin_amdgcn_mfma_f32_16x16x32_bf16(oa[kk], bw, acc, 0, 0, 0);
    }
    const int cc = df * 16 + l15;
    const float bias = pb[cc];
    #pragma unroll
    for (int r = 0; r < 4; ++r) {
      int row = q0 + wv * 16 + g * 4 + r;
      float val = acc[r] + bias + x[((size_t)(b * CD + cc)) * NN + row];
      out[((size_t)(b * NN + row)) * CD + cc] = val;
    }
  }
}

// ---------------------------------------------------------------------------
extern "C" void kernel_launch(void* const* d_in, const int* in_sizes, int n_in,
                              void* d_out, int out_size, void* d_ws, size_t ws_size,
                              hipStream_t stream) {
  (void)in_sizes; (void)n_in; (void)out_size; (void)ws_size;
  const float* x  = (const float*)d_in[0];
  const float* qw = (const float*)d_in[1];
  const float* qb = (const float*)d_in[2];
  const float* kw = (const float*)d_in[3];
  const float* kb = (const float*)d_in[4];
  const float* vw = (const float*)d_in[5];
  const float* vb = (const float*)d_in[6];
  const float* pw = (const float*)d_in[7];
  const float* pb = (const float*)d_in[8];
  float* out = (float*)d_out;

  const size_t SZ = (size_t)NB * NN * CD;  // 4.19M elems per buffer
  __bf16* Qh = (__bf16*)d_ws;              // ws usage: 5 * 8.39 MB = 41.9 MB
  __bf16* Ql = Qh + SZ;
  __bf16* Kh = Ql + SZ;
  __bf16* Kl = Kh + SZ;
  __bf16* Vt = Kl + SZ;

  dim3 grid(512), blk(256);                // 1-D: bid&7 = batch = XCD
  qkv_kernel<<<grid, blk, 0, stream>>>(x, qw, qb, kw, kb, vw, vb,
                                       Qh, Ql, Kh, Kl, Vt);
  attn_kernel<<<grid, blk, 0, stream>>>(Qh, Ql, Kh, Kl, Vt, x, pw, pb, out);
}